// Round 6
// baseline (194.530 us; speedup 1.0000x reference)
//
#include <hip/hip_runtime.h>

#define C_DIM 1280
#define K_DIM 1280      // GEMM K = C
#define N_DIM 2560      // GEMM N = 2C
#define HWSZ 16
#define CHW (C_DIM*HWSZ)

#define BM 256
#define BN 320
#define BK 64
#define NT (K_DIM / BK)   // 20 K-tiles

typedef __bf16 bf16;
typedef __attribute__((ext_vector_type(8))) __bf16 bf16x8;
typedef __attribute__((ext_vector_type(8))) unsigned short u16x8;
typedef __attribute__((ext_vector_type(4))) float f32x4;

template<int V> struct IC { static constexpr int v = V; };

__device__ __forceinline__ void gload_lds16(const void* g, void* l) {
  __builtin_amdgcn_global_load_lds(
      (const __attribute__((address_space(1))) void*)g,
      (__attribute__((address_space(3))) void*)l, 16, 0, 0);
}

// ---------------- image fp32 -> bf16 (RNE via compiler cvt) ----------------
__global__ __launch_bounds__(256) void convert_image(
    const float* __restrict__ in, bf16* __restrict__ outb)
{
  const size_t i = ((size_t)blockIdx.x * 256 + threadIdx.x) * 8;
  const f32x4 a = *(const f32x4*)(in + i);
  const f32x4 b = *(const f32x4*)(in + i + 4);
  bf16x8 o;
  o[0]=(bf16)a[0]; o[1]=(bf16)a[1]; o[2]=(bf16)a[2]; o[3]=(bf16)a[3];
  o[4]=(bf16)b[0]; o[5]=(bf16)b[1]; o[6]=(bf16)b[2]; o[7]=(bf16)b[3];
  *(bf16x8*)(outb + i) = o;
}

// ---------------- h = relu(pose @ W1 + b1), store bf16 ----------------
__global__ __launch_bounds__(256) void pose_mlp1(
    const float* __restrict__ pose, const float* __restrict__ W1,
    const float* __restrict__ b1, bf16* __restrict__ h)
{
  const int c = blockIdx.x * 256 + threadIdx.x;   // grid.x = C_DIM/256
  const int e = blockIdx.y;
  const float* p = pose + e * 9;
  float s = b1[c];
  #pragma unroll
  for (int k = 0; k < 9; k++) s += p[k] * W1[k * C_DIM + c];
  s = s > 0.f ? s : 0.f;
  h[(size_t)e * C_DIM + c] = (bf16)s;
}

// ---------------- W2 (1280 x 2560) -> W2t (2560 x 1280) bf16 ----------------
__global__ __launch_bounds__(256) void transpose_w2(
    const float* __restrict__ W2, bf16* __restrict__ W2t)
{
  __shared__ float tile[32][33];
  int n0 = blockIdx.x * 32;    // 2560/32 = 80
  int k0 = blockIdx.y * 32;    // 1280/32 = 40
  int tx = threadIdx.x;        // 32
  int ty = threadIdx.y;        // 8
  #pragma unroll
  for (int i = 0; i < 32; i += 8)
    tile[ty + i][tx] = W2[(size_t)(k0 + ty + i) * N_DIM + n0 + tx];
  __syncthreads();
  #pragma unroll
  for (int i = 0; i < 32; i += 8)
    W2t[(size_t)(n0 + ty + i) * K_DIM + k0 + tx] = (bf16)tile[tx][ty + i];
}

// ---------------- CSR build: one block, LDS counts/scan/cursor ----------------
__global__ __launch_bounds__(1024) void build_csr(
    const int* __restrict__ dst, const int* __restrict__ src,
    int* __restrict__ offsets, int2* __restrict__ pairs, int E, int N)
{
  __shared__ int buf[1024];
  __shared__ int cur[1024];
  const int t = threadIdx.x;
  buf[t] = 0;
  __syncthreads();
  for (int e = t; e < E; e += 1024) atomicAdd(&buf[dst[e]], 1);
  __syncthreads();
  const int v = buf[t];
  #pragma unroll
  for (int off = 1; off < 1024; off <<= 1) {
    int x = (t >= off) ? buf[t - off] : 0;
    __syncthreads();
    buf[t] += x;
    __syncthreads();
  }
  const int excl = buf[t] - v;
  cur[t] = excl;
  if (t < N) offsets[t] = excl;
  if (t == 0) offsets[N] = E;
  __syncthreads();
  for (int e = t; e < E; e += 1024) {
    const int d = dst[e];
    const int p = atomicAdd(&cur[d], 1);
    pairs[p] = make_int2(e, src[e]);
  }
}

// ---------------- GEMM 256x320 tile, 8 waves, ONE barrier per K-tile ----------------
// Full LDS double-buffer; A-frag register double-buffer; staging front-loaded so the
// per-wave vmcnt(0) at tile end is ~free; MFMA overlaps LDS reads + staging in-flight.
__global__ __launch_bounds__(512, 2) void gemm_sigmoid(
    const bf16* __restrict__ A, const bf16* __restrict__ Bt,
    const float* __restrict__ b2, bf16* __restrict__ Eo)
{
  __shared__ __align__(16) char ldsA[2][BM * BK * 2];   // 2 x 32KB
  __shared__ __align__(16) char ldsB[2][BN * BK * 2];   // 2 x 40KB

  const int tid  = threadIdx.x;
  const int lane = tid & 63;
  const int wid  = tid >> 6;        // 8 waves: 2 (M) x 4 (N)
  const int wr   = wid >> 2;        // 0..1  -> 128-row half
  const int wc   = wid & 3;         // 0..3  -> 80-col slice
  const int fr   = lane & 15;
  const int q    = lane >> 4;       // 0..3
  const int sw   = fr & 7;          // read-swizzle XOR (== row&7 for all frag rows)
  const int g0   = ((q ^ sw) << 4);         // byte offset of kk=0 granule
  const int g1   = (((4 + q) ^ sw) << 4);   // kk=32 granule

  // XCD-aware swizzle (nwg = 256, divisible by 8)
  const int swzb = (blockIdx.x & 7) * 32 + (blockIdx.x >> 3);
  const int mb   = swzb >> 3;       // 0..31
  const int nb   = swzb & 7;        // 0..7
  const long bm  = (long)mb * BM;
  const long bn  = (long)nb * BN;

  const bf16* Agl = A  + bm * K_DIM;
  const bf16* Bgl = Bt + bn * K_DIM;

  f32x4 acc[8][5];
  #pragma unroll
  for (int m = 0; m < 8; m++)
    #pragma unroll
    for (int n = 0; n < 5; n++) acc[m][n] = f32x4{0.f, 0.f, 0.f, 0.f};

  // A chunk p (p=0..3): rows [32p,32p+32) U [128+32p, 128+32p+32)
  auto STAGE_A = [&](int tt, int b, int p) {
    const int wb = (wid < 4) ? (p * 256 + wid * 64) : (1024 + p * 256 + (wid - 4) * 64);
    const int G  = wb + lane;
    const int row = G >> 3, g = G & 7;
    const int kg = (g ^ (row & 7)) << 3;
    gload_lds16(Agl + (size_t)row * K_DIM + tt * BK + kg, ldsA[b] + (size_t)wb * 16);
  };
  // B chunk i (i=0..4): rows [64i, 64i+64)
  auto STAGE_B = [&](int tt, int b, int i) {
    const int wb = i * 512 + wid * 64;
    const int G  = wb + lane;
    const int row = G >> 3, g = G & 7;
    const int kg = (g ^ (row & 7)) << 3;
    gload_lds16(Bgl + (size_t)row * K_DIM + tt * BK + kg, ldsB[b] + (size_t)wb * 16);
  };

  #define LGKM0  do { asm volatile("s_waitcnt lgkmcnt(0)" ::: "memory"); \
                      __builtin_amdgcn_sched_barrier(0); } while (0)
  #define SBAR   do { __builtin_amdgcn_sched_barrier(0); \
                      __builtin_amdgcn_s_barrier(); \
                      __builtin_amdgcn_sched_barrier(0); } while (0)
  #define SB     __builtin_amdgcn_sched_barrier(0)

  // prologue: stage ALL of tile 0, drain, barrier
  STAGE_B(0, 0, 0); STAGE_B(0, 0, 1); STAGE_B(0, 0, 2);
  STAGE_B(0, 0, 3); STAGE_B(0, 0, 4);
  STAGE_A(0, 0, 0); STAGE_A(0, 0, 1); STAGE_A(0, 0, 2); STAGE_A(0, 0, 3);
  asm volatile("s_waitcnt vmcnt(0)" ::: "memory");
  SBAR;

  auto tile_body = [&](auto PFc, int t) {
    constexpr bool PF = (bool)decltype(PFc)::v;
    const int c  = t & 1;
    const int cn = c ^ 1;
    const int tn = t + 1;
    const char* Ab = ldsA[c];
    const char* Bb = ldsB[c];

    bf16x8 bfr[5][2];
    bf16x8 aC[2][2], aN[2][2];

    auto LD_A = [&](int p, bf16x8 dst[2][2]) {
      #pragma unroll
      for (int mm = 0; mm < 2; ++mm) {
        const int ra = (wr * 128 + (2 * p + mm) * 16 + fr) << 7;
        dst[mm][0] = *(const bf16x8*)(Ab + ra + g0);
        dst[mm][1] = *(const bf16x8*)(Ab + ra + g1);
      }
    };
    auto MFMA_P = [&](int p, bf16x8 aa[2][2]) {
      __builtin_amdgcn_s_setprio(1);
      #pragma unroll
      for (int mm = 0; mm < 2; ++mm)
        #pragma unroll
        for (int n = 0; n < 5; ++n) {
          acc[2*p+mm][n] = __builtin_amdgcn_mfma_f32_16x16x32_bf16(aa[mm][0], bfr[n][0], acc[2*p+mm][n], 0, 0, 0);
          acc[2*p+mm][n] = __builtin_amdgcn_mfma_f32_16x16x32_bf16(aa[mm][1], bfr[n][1], acc[2*p+mm][n], 0, 0, 0);
        }
      __builtin_amdgcn_s_setprio(0);
      __builtin_amdgcn_sched_barrier(0);
    };

    // G0: B-frags (10 b128) + A-phase0 frags (4 b128); stage first B chunks of t+1
    #pragma unroll
    for (int n = 0; n < 5; ++n) {
      const int rb = (wc * 80 + n * 16 + fr) << 7;
      bfr[n][0] = *(const bf16x8*)(Bb + rb + g0);
      bfr[n][1] = *(const bf16x8*)(Bb + rb + g1);
    }
    LD_A(0, aC);
    if constexpr (PF) { STAGE_B(tn, cn, 0); STAGE_B(tn, cn, 1); STAGE_B(tn, cn, 2); }
    LGKM0;                               // G0 ready
    LD_A(1, aN);                          // G1 flies under p0's MFMA
    if constexpr (PF) { STAGE_B(tn, cn, 3); STAGE_B(tn, cn, 4); STAGE_A(tn, cn, 0); }
    SB;
    MFMA_P(0, aC);

    LGKM0;                               // G1 ready (long done)
    LD_A(2, aC);
    if constexpr (PF) { STAGE_A(tn, cn, 1); STAGE_A(tn, cn, 2); }
    SB;
    MFMA_P(1, aN);

    LGKM0;                               // G2 ready
    LD_A(3, aN);
    if constexpr (PF) { STAGE_A(tn, cn, 3); }
    SB;
    MFMA_P(2, aC);

    LGKM0;                               // G3 ready
    MFMA_P(3, aN);

    if constexpr (PF) {
      asm volatile("s_waitcnt vmcnt(0)" ::: "memory");  // own staging of t+1 landed
      SBAR;                                              // cross-wave publish
    }
  };

  for (int t = 0; t < NT - 1; ++t) tile_body(IC<1>{}, t);
  tile_body(IC<0>{}, NT - 1);

  // epilogue: sigmoid(acc + b2) -> bf16
  #pragma unroll
  for (int m = 0; m < 8; ++m) {
    const long rowb = bm + wr * 128 + m * 16 + q * 4;
    #pragma unroll
    for (int n = 0; n < 5; ++n) {
      const long col = bn + wc * 80 + n * 16 + fr;
      const float bias = b2[col];
      #pragma unroll
      for (int r = 0; r < 4; ++r) {
        float v = acc[m][n][r] + bias;
        Eo[(rowb + r) * N_DIM + col] = (bf16)(1.f / (1.f + __expf(-v)));
      }
    }
  }
  #undef LGKM0
  #undef SBAR
  #undef SB
}

// ---------------- scatter-mean: out[n] = mean_e(gamma*image_bf16[src]+beta) ----------------
// grid (N, 10); block 256. 128 ch/block; q=t&1 hw-octet, cl=t>>1 channel.
__global__ __launch_bounds__(256) void scatter_mean(
    const ushort* __restrict__ Eo,      // E x 2560 bf16, (gamma,beta) interleaved
    const ushort* __restrict__ imgb16,  // N x C x 16 bf16 bits
    const int2* __restrict__ pairs,     // (eid, src) in CSR order
    const int* __restrict__ offsets,    // N+1
    float* __restrict__ out)            // N x C x 16 fp32
{
  const int n = blockIdx.x;
  const int c0 = blockIdx.y * 128;
  const int t = threadIdx.x;
  const int q = t & 1;
  const int cl = t >> 1;
  const int ca = c0 + cl;
  const int ioff = ca * HWSZ + q * 8;   // element offset into image/out row

  const int beg = offsets[n], end = offsets[n + 1];
  f32x4 aA0{0.f,0.f,0.f,0.f}, aA1{0.f,0.f,0.f,0.f};
  f32x4 aB0{0.f,0.f,0.f,0.f}, aB1{0.f,0.f,0.f,0.f};

  int2 p0{0,0}, p1{0,0};
  if (beg < end) p0 = pairs[beg];
  if (beg + 1 < end) p1 = pairs[beg + 1];

  auto edge = [&](int2 cp, f32x4& x0, f32x4& x1) {
    const u16x8 iv = *(const u16x8*)(imgb16 + (size_t)cp.y * CHW + ioff);
    const uint u = *(const uint*)(Eo + (size_t)cp.x * N_DIM + 2 * ca);
    const float g  = __uint_as_float(u << 16);
    const float be = __uint_as_float(u & 0xffff0000u);
    f32x4 i0, i1;
    i0[0] = __uint_as_float((uint)iv[0] << 16);
    i0[1] = __uint_as_float((uint)iv[1] << 16);
    i0[2] = __uint_as_float((uint)iv[2] << 16);
    i0[3] = __uint_as_float((uint)iv[3] << 16);
    i1[0] = __uint_as_float((uint)iv[4] << 16);
    i1[1] = __uint_as_float((uint)iv[5] << 16);
    i1[2] = __uint_as_float((uint)iv[6] << 16);
    i1[3] = __uint_as_float((uint)iv[7] << 16);
    x0 += g * i0 + be;
    x1 += g * i1 + be;
  };

  int ei = beg;
  for (; ei + 1 < end; ei += 2) {
    const int2 c0p = p0, c1p = p1;
    if (ei + 2 < end) p0 = pairs[ei + 2];
    if (ei + 3 < end) p1 = pairs[ei + 3];
    edge(c0p, aA0, aA1);
    edge(c1p, aB0, aB1);
  }
  if (ei < end) edge(p0, aA0, aA1);

  const int cnt = end - beg;
  const float inv = cnt > 0 ? 1.f / (float)cnt : 0.f;
  const f32x4 r0 = (aA0 + aB0) * inv;
  const f32x4 r1 = (aA1 + aB1) * inv;
  float* ob = out + (size_t)n * CHW + ioff;
  __builtin_nontemporal_store(r0, (f32x4*)ob);
  __builtin_nontemporal_store(r1, (f32x4*)(ob + 4));
}

// ---------------- launch ----------------
extern "C" void kernel_launch(void* const* d_in, const int* in_sizes, int n_in,
                              void* d_out, int out_size, void* d_ws, size_t ws_size,
                              hipStream_t stream) {
  const float* pose  = (const float*)d_in[0];
  const float* image = (const float*)d_in[1];
  const float* W1    = (const float*)d_in[2];
  const float* b1    = (const float*)d_in[3];
  const float* W2    = (const float*)d_in[4];
  const float* b2    = (const float*)d_in[5];
  const int*   src   = (const int*)d_in[6];
  const int*   dst   = (const int*)d_in[7];
  const int E = in_sizes[6];                     // 8192
  const int N = in_sizes[1] / CHW;               // 1024
  float* out = (float*)d_out;

  char* ws = (char*)d_ws;
  size_t off = 0;
  auto alloc = [&](size_t bytes) {
    void* p = ws + off;
    off = (off + bytes + 255) & ~(size_t)255;
    return p;
  };
  bf16* h     = (bf16*)alloc((size_t)E * C_DIM * sizeof(bf16));
  bf16* W2t   = (bf16*)alloc((size_t)N_DIM * K_DIM * sizeof(bf16));
  bf16* Eout  = (bf16*)alloc((size_t)E * N_DIM * sizeof(bf16));
  bf16* imgb  = (bf16*)alloc((size_t)N * CHW * sizeof(bf16));
  int* offs   = (int*)alloc((size_t)(N + 1) * sizeof(int));
  int2* pairs = (int2*)alloc((size_t)E * sizeof(int2));

  // image fp32 -> bf16 (N*CHW/2048 blocks, exact)
  convert_image<<<(N * CHW) / 2048, 256, 0, stream>>>(image, imgb);

  // CSR build (single block, LDS histogram + scan + cursor)
  build_csr<<<1, 1024, 0, stream>>>(dst, src, offs, pairs, E, N);

  // MLP layer 1 + weight transpose
  pose_mlp1<<<dim3(C_DIM / 256, E), 256, 0, stream>>>(pose, W1, b1, h);
  transpose_w2<<<dim3(N_DIM / 32, K_DIM / 32), dim3(32, 8), 0, stream>>>(W2, W2t);

  // MLP layer 2 (bf16 MFMA, 256x320 tile, 1-barrier-per-tile pipeline) + sigmoid
  gemm_sigmoid<<<(E / BM) * (N_DIM / BN), 512, 0, stream>>>(h, W2t, b2, Eout);

  // FiLM + segment mean (bf16 image)
  scatter_mean<<<dim3(N, 10), 256, 0, stream>>>(
      (const ushort*)Eout, (const ushort*)imgb, pairs, offs, out);
}

// Round 7
// 182.235 us; speedup vs baseline: 1.0675x; 1.0675x over previous
//
#include <hip/hip_runtime.h>

#define C_DIM 1280
#define K_DIM 1280      // GEMM K = C
#define N_DIM 2560      // GEMM N = 2C
#define HWSZ 16
#define CHW (C_DIM*HWSZ)

#define BM 128
#define BN 128
#define BK 64
#define NT (K_DIM / BK)   // 20 K-tiles

typedef __bf16 bf16;
typedef __attribute__((ext_vector_type(8))) __bf16 bf16x8;
typedef __attribute__((ext_vector_type(8))) unsigned short u16x8;
typedef __attribute__((ext_vector_type(4))) float f32x4;

__device__ __forceinline__ void gload_lds16(const void* g, void* l) {
  __builtin_amdgcn_global_load_lds(
      (const __attribute__((address_space(1))) void*)g,
      (__attribute__((address_space(3))) void*)l, 16, 0, 0);
}

// ---------------- image fp32 -> bf16 (RNE via compiler cvt) ----------------
__global__ __launch_bounds__(256) void convert_image(
    const float* __restrict__ in, bf16* __restrict__ outb)
{
  const size_t i = ((size_t)blockIdx.x * 256 + threadIdx.x) * 8;
  const f32x4 a = *(const f32x4*)(in + i);
  const f32x4 b = *(const f32x4*)(in + i + 4);
  bf16x8 o;
  o[0]=(bf16)a[0]; o[1]=(bf16)a[1]; o[2]=(bf16)a[2]; o[3]=(bf16)a[3];
  o[4]=(bf16)b[0]; o[5]=(bf16)b[1]; o[6]=(bf16)b[2]; o[7]=(bf16)b[3];
  *(bf16x8*)(outb + i) = o;
}

// ---------------- h = relu(pose @ W1 + b1), store bf16 ----------------
__global__ __launch_bounds__(256) void pose_mlp1(
    const float* __restrict__ pose, const float* __restrict__ W1,
    const float* __restrict__ b1, bf16* __restrict__ h)
{
  const int c = blockIdx.x * 256 + threadIdx.x;   // grid.x = C_DIM/256
  const int e = blockIdx.y;
  const float* p = pose + e * 9;
  float s = b1[c];
  #pragma unroll
  for (int k = 0; k < 9; k++) s += p[k] * W1[k * C_DIM + c];
  s = s > 0.f ? s : 0.f;
  h[(size_t)e * C_DIM + c] = (bf16)s;
}

// ---------------- W2 (1280 x 2560) -> W2t (2560 x 1280) bf16 ----------------
__global__ __launch_bounds__(256) void transpose_w2(
    const float* __restrict__ W2, bf16* __restrict__ W2t)
{
  __shared__ float tile[32][33];
  int n0 = blockIdx.x * 32;    // 2560/32 = 80
  int k0 = blockIdx.y * 32;    // 1280/32 = 40
  int tx = threadIdx.x;        // 32
  int ty = threadIdx.y;        // 8
  #pragma unroll
  for (int i = 0; i < 32; i += 8)
    tile[ty + i][tx] = W2[(size_t)(k0 + ty + i) * N_DIM + n0 + tx];
  __syncthreads();
  #pragma unroll
  for (int i = 0; i < 32; i += 8)
    W2t[(size_t)(n0 + ty + i) * K_DIM + k0 + tx] = (bf16)tile[tx][ty + i];
}

// ---------------- CSR build: one block, LDS counts/scan/cursor ----------------
__global__ __launch_bounds__(1024) void build_csr(
    const int* __restrict__ dst, const int* __restrict__ src,
    int* __restrict__ offsets, int2* __restrict__ pairs, int E, int N)
{
  __shared__ int buf[1024];
  __shared__ int cur[1024];
  const int t = threadIdx.x;
  buf[t] = 0;
  __syncthreads();
  for (int e = t; e < E; e += 1024) atomicAdd(&buf[dst[e]], 1);
  __syncthreads();
  const int v = buf[t];
  #pragma unroll
  for (int off = 1; off < 1024; off <<= 1) {
    int x = (t >= off) ? buf[t - off] : 0;
    __syncthreads();
    buf[t] += x;
    __syncthreads();
  }
  const int excl = buf[t] - v;
  cur[t] = excl;
  if (t < N) offsets[t] = excl;
  if (t == 0) offsets[N] = E;
  __syncthreads();
  for (int e = t; e < E; e += 1024) {
    const int d = dst[e];
    const int p = atomicAdd(&cur[d], 1);
    pairs[p] = make_int2(e, src[e]);
  }
}

// ---------------- GEMM: m97 structure. 128x128 tile, BK=64, 4 waves, ----------------
// single-buffered 32KB LDS -> ~5 blocks/CU. Latency hidden by TLP, not scheduling.
// A: E x 1280 bf16 (row-major); Bt: 2560 x 1280 bf16 (N x K). Eo = sigmoid(A@Bt^T+b2), bf16.
__global__ __launch_bounds__(256) void gemm_sigmoid(
    const bf16* __restrict__ A, const bf16* __restrict__ Bt,
    const float* __restrict__ b2, bf16* __restrict__ Eo)
{
  __shared__ __align__(16) char As[BM * BK * 2];   // 16KB
  __shared__ __align__(16) char Bs[BN * BK * 2];   // 16KB

  const int tid  = threadIdx.x;
  const int lane = tid & 63;
  const int wave = tid >> 6;        // 4 waves: 2 (M) x 2 (N)
  const int wm   = wave >> 1;
  const int wn   = wave & 1;
  const int fr   = lane & 15;
  const int q    = lane >> 4;       // 0..3
  const int sw   = fr & 7;          // read-swizzle XOR (== row&7 for all frag rows)
  const int g0   = ((q ^ sw) << 4);         // byte offset of kk=0 granule
  const int g1   = (((4 + q) ^ sw) << 4);   // kk=32 granule

  // XCD-aware swizzle (nwg = 1280, divisible by 8; 160 blocks per XCD chunk)
  const int swzb = (blockIdx.x & 7) * 160 + (blockIdx.x >> 3);
  const int mb   = swzb / (N_DIM / BN);   // 0..63
  const int nb   = swzb % (N_DIM / BN);   // 0..19
  const long bm  = (long)mb * BM;
  const long bn  = (long)nb * BN;

  const bf16* Agl = A  + bm * K_DIM;
  const bf16* Bgl = Bt + bn * K_DIM;

  f32x4 acc[4][4];
  #pragma unroll
  for (int m = 0; m < 4; m++)
    #pragma unroll
    for (int n = 0; n < 4; n++) acc[m][n] = f32x4{0.f, 0.f, 0.f, 0.f};

  for (int t = 0; t < NT; ++t) {
    const int k0 = t * BK;
    // stage: linear LDS dest (granule G -> byte G*16), inverse-swizzled global src
    #pragma unroll
    for (int i = 0; i < 4; ++i) {
      const int G   = i * 256 + tid;        // 0..1023
      const int row = G >> 3, g = G & 7;
      const int kg  = (g ^ (row & 7)) << 3;
      gload_lds16(Agl + (size_t)row * K_DIM + k0 + kg, As + (size_t)G * 16);
      gload_lds16(Bgl + (size_t)row * K_DIM + k0 + kg, Bs + (size_t)G * 16);
    }
    asm volatile("s_waitcnt vmcnt(0)" ::: "memory");
    __syncthreads();

    bf16x8 a[4][2], b[4][2];
    #pragma unroll
    for (int m = 0; m < 4; ++m) {
      const int ra = (wm * 64 + m * 16 + fr) << 7;
      a[m][0] = *(const bf16x8*)(As + ra + g0);
      a[m][1] = *(const bf16x8*)(As + ra + g1);
    }
    #pragma unroll
    for (int n = 0; n < 4; ++n) {
      const int rb = (wn * 64 + n * 16 + fr) << 7;
      b[n][0] = *(const bf16x8*)(Bs + rb + g0);
      b[n][1] = *(const bf16x8*)(Bs + rb + g1);
    }
    __builtin_amdgcn_s_setprio(1);
    #pragma unroll
    for (int m = 0; m < 4; ++m)
      #pragma unroll
      for (int n = 0; n < 4; ++n) {
        acc[m][n] = __builtin_amdgcn_mfma_f32_16x16x32_bf16(a[m][0], b[n][0], acc[m][n], 0, 0, 0);
        acc[m][n] = __builtin_amdgcn_mfma_f32_16x16x32_bf16(a[m][1], b[n][1], acc[m][n], 0, 0, 0);
      }
    __builtin_amdgcn_s_setprio(0);
    __syncthreads();   // protect LDS before next tile's overwrite
  }

  // epilogue: sigmoid(acc + b2) -> bf16
  #pragma unroll
  for (int m = 0; m < 4; ++m) {
    const long rowb = bm + wm * 64 + m * 16 + q * 4;
    #pragma unroll
    for (int n = 0; n < 4; ++n) {
      const long col = bn + wn * 64 + n * 16 + fr;
      const float bias = b2[col];
      #pragma unroll
      for (int r = 0; r < 4; ++r) {
        float v = acc[m][n][r] + bias;
        Eo[(rowb + r) * N_DIM + col] = (bf16)(1.f / (1.f + __expf(-v)));
      }
    }
  }
}

// ---------------- scatter-mean: out[n] = mean_e(gamma*image_bf16[src]+beta) ----------------
// grid (N, 10); block 256. 128 ch/block; q=t&1 hw-octet, cl=t>>1 channel.
__global__ __launch_bounds__(256) void scatter_mean(
    const ushort* __restrict__ Eo,      // E x 2560 bf16, (gamma,beta) interleaved
    const ushort* __restrict__ imgb16,  // N x C x 16 bf16 bits
    const int2* __restrict__ pairs,     // (eid, src) in CSR order
    const int* __restrict__ offsets,    // N+1
    float* __restrict__ out)            // N x C x 16 fp32
{
  const int n = blockIdx.x;
  const int c0 = blockIdx.y * 128;
  const int t = threadIdx.x;
  const int q = t & 1;
  const int cl = t >> 1;
  const int ca = c0 + cl;
  const int ioff = ca * HWSZ + q * 8;   // element offset into image/out row

  const int beg = offsets[n], end = offsets[n + 1];
  f32x4 aA0{0.f,0.f,0.f,0.f}, aA1{0.f,0.f,0.f,0.f};
  f32x4 aB0{0.f,0.f,0.f,0.f}, aB1{0.f,0.f,0.f,0.f};

  int2 p0{0,0}, p1{0,0};
  if (beg < end) p0 = pairs[beg];
  if (beg + 1 < end) p1 = pairs[beg + 1];

  auto edge = [&](int2 cp, f32x4& x0, f32x4& x1) {
    const u16x8 iv = *(const u16x8*)(imgb16 + (size_t)cp.y * CHW + ioff);
    const uint u = *(const uint*)(Eo + (size_t)cp.x * N_DIM + 2 * ca);
    const float g  = __uint_as_float(u << 16);
    const float be = __uint_as_float(u & 0xffff0000u);
    f32x4 i0, i1;
    i0[0] = __uint_as_float((uint)iv[0] << 16);
    i0[1] = __uint_as_float((uint)iv[1] << 16);
    i0[2] = __uint_as_float((uint)iv[2] << 16);
    i0[3] = __uint_as_float((uint)iv[3] << 16);
    i1[0] = __uint_as_float((uint)iv[4] << 16);
    i1[1] = __uint_as_float((uint)iv[5] << 16);
    i1[2] = __uint_as_float((uint)iv[6] << 16);
    i1[3] = __uint_as_float((uint)iv[7] << 16);
    x0 += g * i0 + be;
    x1 += g * i1 + be;
  };

  int ei = beg;
  for (; ei + 1 < end; ei += 2) {
    const int2 c0p = p0, c1p = p1;
    if (ei + 2 < end) p0 = pairs[ei + 2];
    if (ei + 3 < end) p1 = pairs[ei + 3];
    edge(c0p, aA0, aA1);
    edge(c1p, aB0, aB1);
  }
  if (ei < end) edge(p0, aA0, aA1);

  const int cnt = end - beg;
  const float inv = cnt > 0 ? 1.f / (float)cnt : 0.f;
  const f32x4 r0 = (aA0 + aB0) * inv;
  const f32x4 r1 = (aA1 + aB1) * inv;
  float* ob = out + (size_t)n * CHW + ioff;
  __builtin_nontemporal_store(r0, (f32x4*)ob);
  __builtin_nontemporal_store(r1, (f32x4*)(ob + 4));
}

// ---------------- launch ----------------
extern "C" void kernel_launch(void* const* d_in, const int* in_sizes, int n_in,
                              void* d_out, int out_size, void* d_ws, size_t ws_size,
                              hipStream_t stream) {
  const float* pose  = (const float*)d_in[0];
  const float* image = (const float*)d_in[1];
  const float* W1    = (const float*)d_in[2];
  const float* b1    = (const float*)d_in[3];
  const float* W2    = (const float*)d_in[4];
  const float* b2    = (const float*)d_in[5];
  const int*   src   = (const int*)d_in[6];
  const int*   dst   = (const int*)d_in[7];
  const int E = in_sizes[6];                     // 8192
  const int N = in_sizes[1] / CHW;               // 1024
  float* out = (float*)d_out;

  char* ws = (char*)d_ws;
  size_t off = 0;
  auto alloc = [&](size_t bytes) {
    void* p = ws + off;
    off = (off + bytes + 255) & ~(size_t)255;
    return p;
  };
  bf16* h     = (bf16*)alloc((size_t)E * C_DIM * sizeof(bf16));
  bf16* W2t   = (bf16*)alloc((size_t)N_DIM * K_DIM * sizeof(bf16));
  bf16* Eout  = (bf16*)alloc((size_t)E * N_DIM * sizeof(bf16));
  bf16* imgb  = (bf16*)alloc((size_t)N * CHW * sizeof(bf16));
  int* offs   = (int*)alloc((size_t)(N + 1) * sizeof(int));
  int2* pairs = (int2*)alloc((size_t)E * sizeof(int2));

  // image fp32 -> bf16 (N*CHW/2048 blocks, exact)
  convert_image<<<(N * CHW) / 2048, 256, 0, stream>>>(image, imgb);

  // CSR build (single block, LDS histogram + scan + cursor)
  build_csr<<<1, 1024, 0, stream>>>(dst, src, offs, pairs, E, N);

  // MLP layer 1 + weight transpose
  pose_mlp1<<<dim3(C_DIM / 256, E), 256, 0, stream>>>(pose, W1, b1, h);
  transpose_w2<<<dim3(N_DIM / 32, K_DIM / 32), dim3(32, 8), 0, stream>>>(W2, W2t);

  // MLP layer 2 (bf16 MFMA, m97 128x128 structure, 5 blocks/CU) + sigmoid
  gemm_sigmoid<<<(E / BM) * (N_DIM / BN), 256, 0, stream>>>(h, W2t, b2, Eout);

  // FiLM + segment mean (bf16 image)
  scatter_mean<<<dim3(N, 10), 256, 0, stream>>>(
      (const ushort*)Eout, (const ushort*)imgb, pairs, offs, out);
}

// Round 8
// 179.898 us; speedup vs baseline: 1.0813x; 1.0130x over previous
//
#include <hip/hip_runtime.h>

#define C_DIM 1280
#define K_DIM 1280      // GEMM K = C
#define N_DIM 2560      // GEMM N = 2C
#define HWSZ 16
#define CHW (C_DIM*HWSZ)

#define BM 128
#define BN 128
#define BK 64
#define NT (K_DIM / BK)     // 20 K-tiles
#define NWG_GEMM ((8192/BM)*(N_DIM/BN))   // 1280

typedef __bf16 bf16;
typedef __attribute__((ext_vector_type(8))) __bf16 bf16x8;
typedef __attribute__((ext_vector_type(8))) unsigned short u16x8;
typedef __attribute__((ext_vector_type(4))) float f32x4;

__device__ __forceinline__ void gload_lds16(const void* g, void* l) {
  __builtin_amdgcn_global_load_lds(
      (const __attribute__((address_space(1))) void*)g,
      (__attribute__((address_space(3))) void*)l, 16, 0, 0);
}

// ---------------- prep: block 0 = CSR build; then pose MLP1; then W2 transpose ---------
// grid = 1 + 5*E + 3200, 256 threads.
__global__ __launch_bounds__(256) void prep(
    const float* __restrict__ pose, const float* __restrict__ W1,
    const float* __restrict__ b1, bf16* __restrict__ h,
    const float* __restrict__ W2, bf16* __restrict__ W2t,
    const int* __restrict__ dst, const int* __restrict__ src,
    int* __restrict__ offsets, int2* __restrict__ pairs, int E, int N)
{
  const int b = blockIdx.x;
  const int t = threadIdx.x;

  if (b == 0) {
    // ---- CSR build, 256 threads, N=1024 bins ----
    __shared__ int cnt[1024];
    __shared__ int cur[1024];
    __shared__ int wsum[4];
    #pragma unroll
    for (int i = 0; i < 4; ++i) cnt[t + 256 * i] = 0;
    __syncthreads();
    for (int e = t; e < E; e += 256) atomicAdd(&cnt[dst[e]], 1);
    __syncthreads();
    const int s0 = cnt[4*t], s1 = cnt[4*t+1], s2 = cnt[4*t+2], s3 = cnt[4*t+3];
    const int tot = s0 + s1 + s2 + s3;
    const int lane = t & 63, w = t >> 6;
    int x = tot;
    #pragma unroll
    for (int off = 1; off < 64; off <<= 1) {
      int y = __shfl_up(x, off);
      if (lane >= off) x += y;
    }
    if (lane == 63) wsum[w] = x;
    __syncthreads();
    int woff = 0;
    for (int i = 0; i < w; ++i) woff += wsum[i];
    const int excl = x + woff - tot;    // exclusive prefix of this thread's 4 bins
    const int o0 = excl, o1 = o0 + s0, o2 = o1 + s1, o3 = o2 + s2;
    offsets[4*t] = o0; offsets[4*t+1] = o1; offsets[4*t+2] = o2; offsets[4*t+3] = o3;
    cur[4*t] = o0; cur[4*t+1] = o1; cur[4*t+2] = o2; cur[4*t+3] = o3;
    if (t == 0) offsets[N] = E;
    __syncthreads();
    for (int e = t; e < E; e += 256) {
      const int d = dst[e];
      const int p = atomicAdd(&cur[d], 1);
      pairs[p] = make_int2(e, src[e]);
    }
    return;
  }

  const int pb = b - 1;
  const int NBP = 5 * E;      // C_DIM/256 = 5 blocks per edge
  if (pb < NBP) {
    // ---- h = relu(pose @ W1 + b1), bf16 ----
    const int e = pb / 5;
    const int c = (pb % 5) * 256 + t;
    const float* p = pose + e * 9;
    float s = b1[c];
    #pragma unroll
    for (int k = 0; k < 9; k++) s += p[k] * W1[k * C_DIM + c];
    s = s > 0.f ? s : 0.f;
    h[(size_t)e * C_DIM + c] = (bf16)s;
    return;
  }

  // ---- W2 (1280 x 2560) -> W2t (2560 x 1280) bf16 ----
  const int tb = pb - NBP;              // 0..3199
  __shared__ float tile[32][33];
  const int n0 = (tb % (N_DIM / 32)) * 32;
  const int k0 = (tb / (N_DIM / 32)) * 32;
  const int tx = t & 31;
  const int ty = t >> 5;                // 0..7
  #pragma unroll
  for (int i = 0; i < 32; i += 8)
    tile[ty + i][tx] = W2[(size_t)(k0 + ty + i) * N_DIM + n0 + tx];
  __syncthreads();
  #pragma unroll
  for (int i = 0; i < 32; i += 8)
    W2t[(size_t)(n0 + ty + i) * K_DIM + k0 + tx] = (bf16)tile[tx][ty + i];
}

// ---------------- GEMM (m97 128x128, 5 blocks/CU) + trailing image-convert blocks ------
// blocks [0,1280): Eo = sigmoid(h @ W2t^T + b2) bf16; blocks [1280,...): image fp32->bf16.
__global__ __launch_bounds__(256) void gemm_conv(
    const bf16* __restrict__ A, const bf16* __restrict__ Bt,
    const float* __restrict__ b2, bf16* __restrict__ Eo,
    const float* __restrict__ img32, bf16* __restrict__ imgb)
{
  __shared__ __align__(16) char As[BM * BK * 2];   // 16KB
  __shared__ __align__(16) char Bs[BN * BK * 2];   // 16KB

  if (blockIdx.x >= NWG_GEMM) {
    // ---- convert: 2048 elems/block ----
    const size_t i = ((size_t)(blockIdx.x - NWG_GEMM) * 256 + threadIdx.x) * 8;
    const f32x4 a = *(const f32x4*)(img32 + i);
    const f32x4 b = *(const f32x4*)(img32 + i + 4);
    bf16x8 o;
    o[0]=(bf16)a[0]; o[1]=(bf16)a[1]; o[2]=(bf16)a[2]; o[3]=(bf16)a[3];
    o[4]=(bf16)b[0]; o[5]=(bf16)b[1]; o[6]=(bf16)b[2]; o[7]=(bf16)b[3];
    *(bf16x8*)(imgb + i) = o;
    return;
  }

  const int tid  = threadIdx.x;
  const int lane = tid & 63;
  const int wave = tid >> 6;        // 4 waves: 2 (M) x 2 (N)
  const int wm   = wave >> 1;
  const int wn   = wave & 1;
  const int fr   = lane & 15;
  const int q    = lane >> 4;       // 0..3
  const int sw   = fr & 7;          // read-swizzle XOR (== row&7 for all frag rows)
  const int g0   = ((q ^ sw) << 4);         // byte offset of kk=0 granule
  const int g1   = (((4 + q) ^ sw) << 4);   // kk=32 granule

  // XCD-aware swizzle over the 1280 gemm blocks (160 per XCD chunk)
  const int swzb = (blockIdx.x & 7) * 160 + (blockIdx.x >> 3);
  const int mb   = swzb / (N_DIM / BN);   // 0..63
  const int nb   = swzb % (N_DIM / BN);   // 0..19
  const long bm  = (long)mb * BM;
  const long bn  = (long)nb * BN;

  const bf16* Agl = A  + bm * K_DIM;
  const bf16* Bgl = Bt + bn * K_DIM;

  f32x4 acc[4][4];
  #pragma unroll
  for (int m = 0; m < 4; m++)
    #pragma unroll
    for (int n = 0; n < 4; n++) acc[m][n] = f32x4{0.f, 0.f, 0.f, 0.f};

  for (int t = 0; t < NT; ++t) {
    const int k0 = t * BK;
    // stage: linear LDS dest (granule G -> byte G*16), inverse-swizzled global src
    #pragma unroll
    for (int i = 0; i < 4; ++i) {
      const int G   = i * 256 + tid;        // 0..1023
      const int row = G >> 3, g = G & 7;
      const int kg  = (g ^ (row & 7)) << 3;
      gload_lds16(Agl + (size_t)row * K_DIM + k0 + kg, As + (size_t)G * 16);
      gload_lds16(Bgl + (size_t)row * K_DIM + k0 + kg, Bs + (size_t)G * 16);
    }
    asm volatile("s_waitcnt vmcnt(0)" ::: "memory");
    __syncthreads();

    bf16x8 a[4][2], b[4][2];
    #pragma unroll
    for (int m = 0; m < 4; ++m) {
      const int ra = (wm * 64 + m * 16 + fr) << 7;
      a[m][0] = *(const bf16x8*)(As + ra + g0);
      a[m][1] = *(const bf16x8*)(As + ra + g1);
    }
    #pragma unroll
    for (int n = 0; n < 4; ++n) {
      const int rb = (wn * 64 + n * 16 + fr) << 7;
      b[n][0] = *(const bf16x8*)(Bs + rb + g0);
      b[n][1] = *(const bf16x8*)(Bs + rb + g1);
    }
    __builtin_amdgcn_s_setprio(1);
    #pragma unroll
    for (int m = 0; m < 4; ++m)
      #pragma unroll
      for (int n = 0; n < 4; ++n) {
        acc[m][n] = __builtin_amdgcn_mfma_f32_16x16x32_bf16(a[m][0], b[n][0], acc[m][n], 0, 0, 0);
        acc[m][n] = __builtin_amdgcn_mfma_f32_16x16x32_bf16(a[m][1], b[n][1], acc[m][n], 0, 0, 0);
      }
    __builtin_amdgcn_s_setprio(0);
    __syncthreads();   // protect LDS before next tile's overwrite
  }

  // epilogue: sigmoid(acc + b2) -> bf16
  #pragma unroll
  for (int m = 0; m < 4; ++m) {
    const long rowb = bm + wm * 64 + m * 16 + q * 4;
    #pragma unroll
    for (int n = 0; n < 4; ++n) {
      const long col = bn + wn * 64 + n * 16 + fr;
      const float bias = b2[col];
      #pragma unroll
      for (int r = 0; r < 4; ++r) {
        float v = acc[m][n][r] + bias;
        Eo[(rowb + r) * N_DIM + col] = (bf16)(1.f / (1.f + __expf(-v)));
      }
    }
  }
}

// ---------------- scatter-mean: out[n] = mean_e(gamma*image_bf16[src]+beta) ----------------
// grid (N, 10); block 256. 128 ch/block; q=t&1 hw-octet, cl=t>>1 channel.
__global__ __launch_bounds__(256) void scatter_mean(
    const ushort* __restrict__ Eo,      // E x 2560 bf16, (gamma,beta) interleaved
    const ushort* __restrict__ imgb16,  // N x C x 16 bf16 bits
    const int2* __restrict__ pairs,     // (eid, src) in CSR order
    const int* __restrict__ offsets,    // N+1
    float* __restrict__ out)            // N x C x 16 fp32
{
  const int n = blockIdx.x;
  const int c0 = blockIdx.y * 128;
  const int t = threadIdx.x;
  const int q = t & 1;
  const int cl = t >> 1;
  const int ca = c0 + cl;
  const int ioff = ca * HWSZ + q * 8;   // element offset into image/out row

  const int beg = offsets[n], end = offsets[n + 1];
  f32x4 aA0{0.f,0.f,0.f,0.f}, aA1{0.f,0.f,0.f,0.f};
  f32x4 aB0{0.f,0.f,0.f,0.f}, aB1{0.f,0.f,0.f,0.f};

  int2 p0{0,0}, p1{0,0};
  if (beg < end) p0 = pairs[beg];
  if (beg + 1 < end) p1 = pairs[beg + 1];

  auto edge = [&](int2 cp, f32x4& x0, f32x4& x1) {
    const u16x8 iv = *(const u16x8*)(imgb16 + (size_t)cp.y * CHW + ioff);
    const uint u = *(const uint*)(Eo + (size_t)cp.x * N_DIM + 2 * ca);
    const float g  = __uint_as_float(u << 16);
    const float be = __uint_as_float(u & 0xffff0000u);
    f32x4 i0, i1;
    i0[0] = __uint_as_float((uint)iv[0] << 16);
    i0[1] = __uint_as_float((uint)iv[1] << 16);
    i0[2] = __uint_as_float((uint)iv[2] << 16);
    i0[3] = __uint_as_float((uint)iv[3] << 16);
    i1[0] = __uint_as_float((uint)iv[4] << 16);
    i1[1] = __uint_as_float((uint)iv[5] << 16);
    i1[2] = __uint_as_float((uint)iv[6] << 16);
    i1[3] = __uint_as_float((uint)iv[7] << 16);
    x0 += g * i0 + be;
    x1 += g * i1 + be;
  };

  int ei = beg;
  for (; ei + 1 < end; ei += 2) {
    const int2 c0p = p0, c1p = p1;
    if (ei + 2 < end) p0 = pairs[ei + 2];
    if (ei + 3 < end) p1 = pairs[ei + 3];
    edge(c0p, aA0, aA1);
    edge(c1p, aB0, aB1);
  }
  if (ei < end) edge(p0, aA0, aA1);

  const int cnt = end - beg;
  const float inv = cnt > 0 ? 1.f / (float)cnt : 0.f;
  const f32x4 r0 = (aA0 + aB0) * inv;
  const f32x4 r1 = (aA1 + aB1) * inv;
  float* ob = out + (size_t)n * CHW + ioff;
  __builtin_nontemporal_store(r0, (f32x4*)ob);
  __builtin_nontemporal_store(r1, (f32x4*)(ob + 4));
}

// ---------------- launch ----------------
extern "C" void kernel_launch(void* const* d_in, const int* in_sizes, int n_in,
                              void* d_out, int out_size, void* d_ws, size_t ws_size,
                              hipStream_t stream) {
  const float* pose  = (const float*)d_in[0];
  const float* image = (const float*)d_in[1];
  const float* W1    = (const float*)d_in[2];
  const float* b1    = (const float*)d_in[3];
  const float* W2    = (const float*)d_in[4];
  const float* b2    = (const float*)d_in[5];
  const int*   src   = (const int*)d_in[6];
  const int*   dst   = (const int*)d_in[7];
  const int E = in_sizes[6];                     // 8192
  const int N = in_sizes[1] / CHW;               // 1024
  float* out = (float*)d_out;

  char* ws = (char*)d_ws;
  size_t off = 0;
  auto alloc = [&](size_t bytes) {
    void* p = ws + off;
    off = (off + bytes + 255) & ~(size_t)255;
    return p;
  };
  bf16* h     = (bf16*)alloc((size_t)E * C_DIM * sizeof(bf16));
  bf16* W2t   = (bf16*)alloc((size_t)N_DIM * K_DIM * sizeof(bf16));
  bf16* Eout  = (bf16*)alloc((size_t)E * N_DIM * sizeof(bf16));
  bf16* imgb  = (bf16*)alloc((size_t)N * CHW * sizeof(bf16));
  int* offs   = (int*)alloc((size_t)(N + 1) * sizeof(int));
  int2* pairs = (int2*)alloc((size_t)E * sizeof(int2));

  // prep: CSR (block 0) + pose MLP1 (5*E blocks) + W2 transpose (3200 blocks)
  const int nb_prep = 1 + 5 * E + (N_DIM / 32) * (K_DIM / 32);
  prep<<<nb_prep, 256, 0, stream>>>(pose, W1, b1, h, W2, W2t, dst, src,
                                    offs, pairs, E, N);

  // GEMM (1280 blocks) + image convert (10240 blocks) in one launch
  const int nb_gemm = NWG_GEMM + (N * CHW) / 2048;
  gemm_conv<<<nb_gemm, 256, 0, stream>>>(h, W2t, b2, Eout, image, imgb);

  // FiLM + segment mean (bf16 image)
  scatter_mean<<<dim3(N, 10), 256, 0, stream>>>(
      (const ushort*)Eout, (const ushort*)imgb, pairs, offs, out);
}

// Round 9
// 171.261 us; speedup vs baseline: 1.1359x; 1.0504x over previous
//
#include <hip/hip_runtime.h>

#define C_DIM 1280
#define K_DIM 1280      // GEMM K = C
#define N_DIM 2560      // GEMM N = 2C
#define HWSZ 16
#define CHW (C_DIM*HWSZ)

#define BM 128
#define BN 128
#define BK 64
#define NT (K_DIM / BK)     // 20 K-tiles

typedef __bf16 bf16;
typedef __attribute__((ext_vector_type(8))) __bf16 bf16x8;
typedef __attribute__((ext_vector_type(8))) unsigned short u16x8;
typedef __attribute__((ext_vector_type(4))) float f32x4;

__device__ __forceinline__ void gload_lds16(const void* g, void* l) {
  __builtin_amdgcn_global_load_lds(
      (const __attribute__((address_space(1))) void*)g,
      (__attribute__((address_space(3))) void*)l, 16, 0, 0);
}

// ---------------- prep: CSR (block 0) + pose MLP1 + W2 transpose + image convert -------
// grid = 1 + 5*E + 3200 + 10240, 256 threads, <=8.5KB LDS.
__global__ __launch_bounds__(256) void prep(
    const float* __restrict__ pose, const float* __restrict__ W1,
    const float* __restrict__ b1, bf16* __restrict__ h,
    const float* __restrict__ W2, bf16* __restrict__ W2t,
    const float* __restrict__ img32, bf16* __restrict__ imgb,
    const int* __restrict__ dst, const int* __restrict__ src,
    int* __restrict__ offsets, int2* __restrict__ pairs, int E, int N)
{
  const int b = blockIdx.x;
  const int t = threadIdx.x;
  const int NBP = 5 * E;                      // pose blocks (C_DIM/256 = 5 per edge)
  const int NBT = (N_DIM / 32) * (K_DIM / 32); // 3200 transpose blocks

  if (b == 0) {
    // ---- CSR build, 256 threads, N=1024 bins ----
    __shared__ int cnt[1024];
    __shared__ int cur[1024];
    __shared__ int wsum[4];
    #pragma unroll
    for (int i = 0; i < 4; ++i) cnt[t + 256 * i] = 0;
    __syncthreads();
    for (int e = t; e < E; e += 256) atomicAdd(&cnt[dst[e]], 1);
    __syncthreads();
    const int s0 = cnt[4*t], s1 = cnt[4*t+1], s2 = cnt[4*t+2], s3 = cnt[4*t+3];
    const int tot = s0 + s1 + s2 + s3;
    const int lane = t & 63, w = t >> 6;
    int x = tot;
    #pragma unroll
    for (int off = 1; off < 64; off <<= 1) {
      int y = __shfl_up(x, off);
      if (lane >= off) x += y;
    }
    if (lane == 63) wsum[w] = x;
    __syncthreads();
    int woff = 0;
    for (int i = 0; i < w; ++i) woff += wsum[i];
    const int excl = x + woff - tot;    // exclusive prefix of this thread's 4 bins
    const int o0 = excl, o1 = o0 + s0, o2 = o1 + s1, o3 = o2 + s2;
    offsets[4*t] = o0; offsets[4*t+1] = o1; offsets[4*t+2] = o2; offsets[4*t+3] = o3;
    cur[4*t] = o0; cur[4*t+1] = o1; cur[4*t+2] = o2; cur[4*t+3] = o3;
    if (t == 0) offsets[N] = E;
    __syncthreads();
    for (int e = t; e < E; e += 256) {
      const int d = dst[e];
      const int p = atomicAdd(&cur[d], 1);
      pairs[p] = make_int2(e, src[e]);
    }
    return;
  }

  const int pb = b - 1;
  if (pb < NBP) {
    // ---- h = relu(pose @ W1 + b1), bf16 ----
    const int e = pb / 5;
    const int c = (pb % 5) * 256 + t;
    const float* p = pose + e * 9;
    float s = b1[c];
    #pragma unroll
    for (int k = 0; k < 9; k++) s += p[k] * W1[k * C_DIM + c];
    s = s > 0.f ? s : 0.f;
    h[(size_t)e * C_DIM + c] = (bf16)s;
    return;
  }

  if (pb < NBP + NBT) {
    // ---- W2 (1280 x 2560) -> W2t (2560 x 1280) bf16 ----
    const int tb = pb - NBP;              // 0..3199
    __shared__ float tile[32][33];
    const int n0 = (tb % (N_DIM / 32)) * 32;
    const int k0 = (tb / (N_DIM / 32)) * 32;
    const int tx = t & 31;
    const int ty = t >> 5;                // 0..7
    #pragma unroll
    for (int i = 0; i < 32; i += 8)
      tile[ty + i][tx] = W2[(size_t)(k0 + ty + i) * N_DIM + n0 + tx];
    __syncthreads();
    #pragma unroll
    for (int i = 0; i < 32; i += 8)
      W2t[(size_t)(n0 + ty + i) * K_DIM + k0 + tx] = (bf16)tile[tx][ty + i];
    return;
  }

  // ---- image fp32 -> bf16, 2048 elems/block ----
  const size_t i = ((size_t)(pb - NBP - NBT) * 256 + t) * 8;
  const f32x4 a = *(const f32x4*)(img32 + i);
  const f32x4 bb = *(const f32x4*)(img32 + i + 4);
  bf16x8 o;
  o[0]=(bf16)a[0]; o[1]=(bf16)a[1]; o[2]=(bf16)a[2]; o[3]=(bf16)a[3];
  o[4]=(bf16)bb[0]; o[5]=(bf16)bb[1]; o[6]=(bf16)bb[2]; o[7]=(bf16)bb[3];
  *(bf16x8*)(imgb + i) = o;
}

// ---------------- GEMM: m97 structure. 128x128 tile, BK=64, 4 waves, ----------------
// single-buffered 32KB LDS -> 5 blocks/CU. Latency hidden by TLP.
__global__ __launch_bounds__(256) void gemm_sigmoid(
    const bf16* __restrict__ A, const bf16* __restrict__ Bt,
    const float* __restrict__ b2, bf16* __restrict__ Eo)
{
  __shared__ __align__(16) char As[BM * BK * 2];   // 16KB
  __shared__ __align__(16) char Bs[BN * BK * 2];   // 16KB

  const int tid  = threadIdx.x;
  const int lane = tid & 63;
  const int wave = tid >> 6;        // 4 waves: 2 (M) x 2 (N)
  const int wm   = wave >> 1;
  const int wn   = wave & 1;
  const int fr   = lane & 15;
  const int q    = lane >> 4;       // 0..3
  const int sw   = fr & 7;          // read-swizzle XOR (== row&7 for all frag rows)
  const int g0   = ((q ^ sw) << 4);         // byte offset of kk=0 granule
  const int g1   = (((4 + q) ^ sw) << 4);   // kk=32 granule

  // XCD-aware swizzle (nwg = 1280, divisible by 8; 160 blocks per XCD chunk)
  const int swzb = (blockIdx.x & 7) * 160 + (blockIdx.x >> 3);
  const int mb   = swzb / (N_DIM / BN);   // 0..63
  const int nb   = swzb % (N_DIM / BN);   // 0..19
  const long bm  = (long)mb * BM;
  const long bn  = (long)nb * BN;

  const bf16* Agl = A  + bm * K_DIM;
  const bf16* Bgl = Bt + bn * K_DIM;

  f32x4 acc[4][4];
  #pragma unroll
  for (int m = 0; m < 4; m++)
    #pragma unroll
    for (int n = 0; n < 4; n++) acc[m][n] = f32x4{0.f, 0.f, 0.f, 0.f};

  for (int t = 0; t < NT; ++t) {
    const int k0 = t * BK;
    // stage: linear LDS dest (granule G -> byte G*16), inverse-swizzled global src
    #pragma unroll
    for (int i = 0; i < 4; ++i) {
      const int G   = i * 256 + tid;        // 0..1023
      const int row = G >> 3, g = G & 7;
      const int kg  = (g ^ (row & 7)) << 3;
      gload_lds16(Agl + (size_t)row * K_DIM + k0 + kg, As + (size_t)G * 16);
      gload_lds16(Bgl + (size_t)row * K_DIM + k0 + kg, Bs + (size_t)G * 16);
    }
    asm volatile("s_waitcnt vmcnt(0)" ::: "memory");
    __syncthreads();

    bf16x8 a[4][2], b[4][2];
    #pragma unroll
    for (int m = 0; m < 4; ++m) {
      const int ra = (wm * 64 + m * 16 + fr) << 7;
      a[m][0] = *(const bf16x8*)(As + ra + g0);
      a[m][1] = *(const bf16x8*)(As + ra + g1);
    }
    #pragma unroll
    for (int n = 0; n < 4; ++n) {
      const int rb = (wn * 64 + n * 16 + fr) << 7;
      b[n][0] = *(const bf16x8*)(Bs + rb + g0);
      b[n][1] = *(const bf16x8*)(Bs + rb + g1);
    }
    __builtin_amdgcn_s_setprio(1);
    #pragma unroll
    for (int m = 0; m < 4; ++m)
      #pragma unroll
      for (int n = 0; n < 4; ++n) {
        acc[m][n] = __builtin_amdgcn_mfma_f32_16x16x32_bf16(a[m][0], b[n][0], acc[m][n], 0, 0, 0);
        acc[m][n] = __builtin_amdgcn_mfma_f32_16x16x32_bf16(a[m][1], b[n][1], acc[m][n], 0, 0, 0);
      }
    __builtin_amdgcn_s_setprio(0);
    __syncthreads();   // protect LDS before next tile's overwrite
  }

  // epilogue: sigmoid(acc + b2) -> bf16
  #pragma unroll
  for (int m = 0; m < 4; ++m) {
    const long rowb = bm + wm * 64 + m * 16 + q * 4;
    #pragma unroll
    for (int n = 0; n < 4; ++n) {
      const long col = bn + wn * 64 + n * 16 + fr;
      const float bias = b2[col];
      #pragma unroll
      for (int r = 0; r < 4; ++r) {
        float v = acc[m][n][r] + bias;
        Eo[(rowb + r) * N_DIM + col] = (bf16)(1.f / (1.f + __expf(-v)));
      }
    }
  }
}

// ---------------- scatter-mean: out[n] = mean_e(gamma*image_bf16[src]+beta) ----------------
// grid (N, 10); block 256. 128 ch/block; q=t&1 hw-octet, cl=t>>1 channel.
__global__ __launch_bounds__(256) void scatter_mean(
    const ushort* __restrict__ Eo,      // E x 2560 bf16, (gamma,beta) interleaved
    const ushort* __restrict__ imgb16,  // N x C x 16 bf16 bits
    const int2* __restrict__ pairs,     // (eid, src) in CSR order
    const int* __restrict__ offsets,    // N+1
    float* __restrict__ out)            // N x C x 16 fp32
{
  const int n = blockIdx.x;
  const int c0 = blockIdx.y * 128;
  const int t = threadIdx.x;
  const int q = t & 1;
  const int cl = t >> 1;
  const int ca = c0 + cl;
  const int ioff = ca * HWSZ + q * 8;   // element offset into image/out row

  const int beg = offsets[n], end = offsets[n + 1];
  f32x4 aA0{0.f,0.f,0.f,0.f}, aA1{0.f,0.f,0.f,0.f};
  f32x4 aB0{0.f,0.f,0.f,0.f}, aB1{0.f,0.f,0.f,0.f};

  int2 p0{0,0}, p1{0,0};
  if (beg < end) p0 = pairs[beg];
  if (beg + 1 < end) p1 = pairs[beg + 1];

  auto edge = [&](int2 cp, f32x4& x0, f32x4& x1) {
    const u16x8 iv = *(const u16x8*)(imgb16 + (size_t)cp.y * CHW + ioff);
    const uint u = *(const uint*)(Eo + (size_t)cp.x * N_DIM + 2 * ca);
    const float g  = __uint_as_float(u << 16);
    const float be = __uint_as_float(u & 0xffff0000u);
    f32x4 i0, i1;
    i0[0] = __uint_as_float((uint)iv[0] << 16);
    i0[1] = __uint_as_float((uint)iv[1] << 16);
    i0[2] = __uint_as_float((uint)iv[2] << 16);
    i0[3] = __uint_as_float((uint)iv[3] << 16);
    i1[0] = __uint_as_float((uint)iv[4] << 16);
    i1[1] = __uint_as_float((uint)iv[5] << 16);
    i1[2] = __uint_as_float((uint)iv[6] << 16);
    i1[3] = __uint_as_float((uint)iv[7] << 16);
    x0 += g * i0 + be;
    x1 += g * i1 + be;
  };

  int ei = beg;
  for (; ei + 1 < end; ei += 2) {
    const int2 c0p = p0, c1p = p1;
    if (ei + 2 < end) p0 = pairs[ei + 2];
    if (ei + 3 < end) p1 = pairs[ei + 3];
    edge(c0p, aA0, aA1);
    edge(c1p, aB0, aB1);
  }
  if (ei < end) edge(p0, aA0, aA1);

  const int cnt = end - beg;
  const float inv = cnt > 0 ? 1.f / (float)cnt : 0.f;
  const f32x4 r0 = (aA0 + aB0) * inv;
  const f32x4 r1 = (aA1 + aB1) * inv;
  float* ob = out + (size_t)n * CHW + ioff;
  __builtin_nontemporal_store(r0, (f32x4*)ob);
  __builtin_nontemporal_store(r1, (f32x4*)(ob + 4));
}

// ---------------- launch ----------------
extern "C" void kernel_launch(void* const* d_in, const int* in_sizes, int n_in,
                              void* d_out, int out_size, void* d_ws, size_t ws_size,
                              hipStream_t stream) {
  const float* pose  = (const float*)d_in[0];
  const float* image = (const float*)d_in[1];
  const float* W1    = (const float*)d_in[2];
  const float* b1    = (const float*)d_in[3];
  const float* W2    = (const float*)d_in[4];
  const float* b2    = (const float*)d_in[5];
  const int*   src   = (const int*)d_in[6];
  const int*   dst   = (const int*)d_in[7];
  const int E = in_sizes[6];                     // 8192
  const int N = in_sizes[1] / CHW;               // 1024
  float* out = (float*)d_out;

  char* ws = (char*)d_ws;
  size_t off = 0;
  auto alloc = [&](size_t bytes) {
    void* p = ws + off;
    off = (off + bytes + 255) & ~(size_t)255;
    return p;
  };
  bf16* h     = (bf16*)alloc((size_t)E * C_DIM * sizeof(bf16));
  bf16* W2t   = (bf16*)alloc((size_t)N_DIM * K_DIM * sizeof(bf16));
  bf16* Eout  = (bf16*)alloc((size_t)E * N_DIM * sizeof(bf16));
  bf16* imgb  = (bf16*)alloc((size_t)N * CHW * sizeof(bf16));
  int* offs   = (int*)alloc((size_t)(N + 1) * sizeof(int));
  int2* pairs = (int2*)alloc((size_t)E * sizeof(int2));

  // prep: CSR + pose MLP1 + W2 transpose + image convert, one launch
  const int nb_prep = 1 + 5 * E + (N_DIM / 32) * (K_DIM / 32) + (N * CHW) / 2048;
  prep<<<nb_prep, 256, 0, stream>>>(pose, W1, b1, h, W2, W2t, image, imgb,
                                    dst, src, offs, pairs, E, N);

  // GEMM standalone (m97 128x128 structure, 5 blocks/CU)
  gemm_sigmoid<<<(E / BM) * (N_DIM / BN), 256, 0, stream>>>(h, W2t, b2, Eout);

  // FiLM + segment mean (bf16 image)
  scatter_mean<<<dim3(N, 10), 256, 0, stream>>>(
      (const ushort*)Eout, (const ushort*)imgb, pairs, offs, out);
}

// Round 10
// 168.532 us; speedup vs baseline: 1.1543x; 1.0162x over previous
//
#include <hip/hip_runtime.h>

#define C_DIM 1280
#define K_DIM 1280      // GEMM K = C
#define N_DIM 2560      // GEMM N = 2C
#define HWSZ 16
#define CHW (C_DIM*HWSZ)

#define BM 128
#define BN 128
#define BK 64
#define NT (K_DIM / BK)     // 20 K-tiles

#define EPB 32              // edges per pose-MLP block

typedef __bf16 bf16;
typedef __attribute__((ext_vector_type(8))) __bf16 bf16x8;
typedef __attribute__((ext_vector_type(8))) unsigned short u16x8;
typedef __attribute__((ext_vector_type(4))) float f32x4;

__device__ __forceinline__ void gload_lds16(const void* g, void* l) {
  __builtin_amdgcn_global_load_lds(
      (const __attribute__((address_space(1))) void*)g,
      (__attribute__((address_space(3))) void*)l, 16, 0, 0);
}

// ---------------- prep: CSR (block 0) + batched pose MLP1 + W2 transpose + convert ------
// grid = 1 + (E/32)*5 + 3200 + 10240, 256 threads.
__global__ __launch_bounds__(256) void prep(
    const float* __restrict__ pose, const float* __restrict__ W1,
    const float* __restrict__ b1, bf16* __restrict__ h,
    const float* __restrict__ W2, bf16* __restrict__ W2t,
    const float* __restrict__ img32, bf16* __restrict__ imgb,
    const int* __restrict__ dst, const int* __restrict__ src,
    int* __restrict__ offsets, int2* __restrict__ pairs, int E, int N)
{
  const int b = blockIdx.x;
  const int t = threadIdx.x;
  const int NBP = (E / EPB) * 5;               // 1280 pose blocks
  const int NBT = (N_DIM / 32) * (K_DIM / 32); // 3200 transpose blocks

  if (b == 0) {
    // ---- CSR build, 256 threads, N=1024 bins ----
    __shared__ int cnt[1024];
    __shared__ int cur[1024];
    __shared__ int wsum[4];
    #pragma unroll
    for (int i = 0; i < 4; ++i) cnt[t + 256 * i] = 0;
    __syncthreads();
    for (int e = t; e < E; e += 256) atomicAdd(&cnt[dst[e]], 1);
    __syncthreads();
    const int s0 = cnt[4*t], s1 = cnt[4*t+1], s2 = cnt[4*t+2], s3 = cnt[4*t+3];
    const int tot = s0 + s1 + s2 + s3;
    const int lane = t & 63, w = t >> 6;
    int x = tot;
    #pragma unroll
    for (int off = 1; off < 64; off <<= 1) {
      int y = __shfl_up(x, off);
      if (lane >= off) x += y;
    }
    if (lane == 63) wsum[w] = x;
    __syncthreads();
    int woff = 0;
    for (int i = 0; i < w; ++i) woff += wsum[i];
    const int excl = x + woff - tot;    // exclusive prefix of this thread's 4 bins
    const int o0 = excl, o1 = o0 + s0, o2 = o1 + s1, o3 = o2 + s2;
    offsets[4*t] = o0; offsets[4*t+1] = o1; offsets[4*t+2] = o2; offsets[4*t+3] = o3;
    cur[4*t] = o0; cur[4*t+1] = o1; cur[4*t+2] = o2; cur[4*t+3] = o3;
    if (t == 0) offsets[N] = E;
    __syncthreads();
    for (int e = t; e < E; e += 256) {
      const int d = dst[e];
      const int p = atomicAdd(&cur[d], 1);
      pairs[p] = make_int2(e, src[e]);
    }
    return;
  }

  const int pb = b - 1;
  if (pb < NBP) {
    // ---- h = relu(pose @ W1 + b1): 32 edges x 256 channels per block ----
    const int eg = pb / 5;             // edge group
    const int cc = pb % 5;             // channel chunk
    const int c  = cc * 256 + t;
    const int e0 = eg * EPB;
    float w[9];
    #pragma unroll
    for (int k = 0; k < 9; ++k) w[k] = W1[k * C_DIM + c];
    const float bias = b1[c];
    #pragma unroll 4
    for (int i = 0; i < EPB; ++i) {
      const float* p = pose + (size_t)(e0 + i) * 9;
      float s = bias;
      #pragma unroll
      for (int k = 0; k < 9; ++k) s += p[k] * w[k];
      s = s > 0.f ? s : 0.f;
      h[(size_t)(e0 + i) * C_DIM + c] = (bf16)s;
    }
    return;
  }

  if (pb < NBP + NBT) {
    // ---- W2 (1280 x 2560) -> W2t (2560 x 1280) bf16 ----
    const int tb = pb - NBP;              // 0..3199
    __shared__ float tile[32][33];
    const int n0 = (tb % (N_DIM / 32)) * 32;
    const int k0 = (tb / (N_DIM / 32)) * 32;
    const int tx = t & 31;
    const int ty = t >> 5;                // 0..7
    #pragma unroll
    for (int i = 0; i < 32; i += 8)
      tile[ty + i][tx] = W2[(size_t)(k0 + ty + i) * N_DIM + n0 + tx];
    __syncthreads();
    #pragma unroll
    for (int i = 0; i < 32; i += 8)
      W2t[(size_t)(n0 + ty + i) * K_DIM + k0 + tx] = (bf16)tile[tx][ty + i];
    return;
  }

  // ---- image fp32 -> bf16, 2048 elems/block ----
  const size_t i = ((size_t)(pb - NBP - NBT) * 256 + t) * 8;
  const f32x4 a = *(const f32x4*)(img32 + i);
  const f32x4 bb = *(const f32x4*)(img32 + i + 4);
  bf16x8 o;
  o[0]=(bf16)a[0]; o[1]=(bf16)a[1]; o[2]=(bf16)a[2]; o[3]=(bf16)a[3];
  o[4]=(bf16)bb[0]; o[5]=(bf16)bb[1]; o[6]=(bf16)bb[2]; o[7]=(bf16)bb[3];
  *(bf16x8*)(imgb + i) = o;
}

// ---------------- GEMM: m97 structure. 128x128 tile, BK=64, 4 waves, ----------------
// single-buffered 32KB LDS -> 5 blocks/CU. Latency hidden by TLP.
__global__ __launch_bounds__(256) void gemm_sigmoid(
    const bf16* __restrict__ A, const bf16* __restrict__ Bt,
    const float* __restrict__ b2, bf16* __restrict__ Eo)
{
  __shared__ __align__(16) char As[BM * BK * 2];   // 16KB
  __shared__ __align__(16) char Bs[BN * BK * 2];   // 16KB

  const int tid  = threadIdx.x;
  const int lane = tid & 63;
  const int wave = tid >> 6;        // 4 waves: 2 (M) x 2 (N)
  const int wm   = wave >> 1;
  const int wn   = wave & 1;
  const int fr   = lane & 15;
  const int q    = lane >> 4;       // 0..3
  const int sw   = fr & 7;          // read-swizzle XOR (== row&7 for all frag rows)
  const int g0   = ((q ^ sw) << 4);         // byte offset of kk=0 granule
  const int g1   = (((4 + q) ^ sw) << 4);   // kk=32 granule

  // XCD-aware swizzle (nwg = 1280, divisible by 8; 160 blocks per XCD chunk)
  const int swzb = (blockIdx.x & 7) * 160 + (blockIdx.x >> 3);
  const int mb   = swzb / (N_DIM / BN);   // 0..63
  const int nb   = swzb % (N_DIM / BN);   // 0..19
  const long bm  = (long)mb * BM;
  const long bn  = (long)nb * BN;

  const bf16* Agl = A  + bm * K_DIM;
  const bf16* Bgl = Bt + bn * K_DIM;

  f32x4 acc[4][4];
  #pragma unroll
  for (int m = 0; m < 4; m++)
    #pragma unroll
    for (int n = 0; n < 4; n++) acc[m][n] = f32x4{0.f, 0.f, 0.f, 0.f};

  for (int t = 0; t < NT; ++t) {
    const int k0 = t * BK;
    // stage: linear LDS dest (granule G -> byte G*16), inverse-swizzled global src
    #pragma unroll
    for (int i = 0; i < 4; ++i) {
      const int G   = i * 256 + tid;        // 0..1023
      const int row = G >> 3, g = G & 7;
      const int kg  = (g ^ (row & 7)) << 3;
      gload_lds16(Agl + (size_t)row * K_DIM + k0 + kg, As + (size_t)G * 16);
      gload_lds16(Bgl + (size_t)row * K_DIM + k0 + kg, Bs + (size_t)G * 16);
    }
    asm volatile("s_waitcnt vmcnt(0)" ::: "memory");
    __syncthreads();

    bf16x8 a[4][2], b[4][2];
    #pragma unroll
    for (int m = 0; m < 4; ++m) {
      const int ra = (wm * 64 + m * 16 + fr) << 7;
      a[m][0] = *(const bf16x8*)(As + ra + g0);
      a[m][1] = *(const bf16x8*)(As + ra + g1);
    }
    #pragma unroll
    for (int n = 0; n < 4; ++n) {
      const int rb = (wn * 64 + n * 16 + fr) << 7;
      b[n][0] = *(const bf16x8*)(Bs + rb + g0);
      b[n][1] = *(const bf16x8*)(Bs + rb + g1);
    }
    __builtin_amdgcn_s_setprio(1);
    #pragma unroll
    for (int m = 0; m < 4; ++m)
      #pragma unroll
      for (int n = 0; n < 4; ++n) {
        acc[m][n] = __builtin_amdgcn_mfma_f32_16x16x32_bf16(a[m][0], b[n][0], acc[m][n], 0, 0, 0);
        acc[m][n] = __builtin_amdgcn_mfma_f32_16x16x32_bf16(a[m][1], b[n][1], acc[m][n], 0, 0, 0);
      }
    __builtin_amdgcn_s_setprio(0);
    __syncthreads();   // protect LDS before next tile's overwrite
  }

  // epilogue: sigmoid(acc + b2) -> bf16
  #pragma unroll
  for (int m = 0; m < 4; ++m) {
    const long rowb = bm + wm * 64 + m * 16 + q * 4;
    #pragma unroll
    for (int n = 0; n < 4; ++n) {
      const long col = bn + wn * 64 + n * 16 + fr;
      const float bias = b2[col];
      #pragma unroll
      for (int r = 0; r < 4; ++r) {
        float v = acc[m][n][r] + bias;
        Eo[(rowb + r) * N_DIM + col] = (bf16)(1.f / (1.f + __expf(-v)));
      }
    }
  }
}

// ---------------- scatter-mean: out[n] = mean_e(gamma*image_bf16[src]+beta) ----------------
// grid (N, 10); block 256. 128 ch/block; q=t&1 hw-octet, cl=t>>1 channel.
__global__ __launch_bounds__(256) void scatter_mean(
    const ushort* __restrict__ Eo,      // E x 2560 bf16, (gamma,beta) interleaved
    const ushort* __restrict__ imgb16,  // N x C x 16 bf16 bits
    const int2* __restrict__ pairs,     // (eid, src) in CSR order
    const int* __restrict__ offsets,    // N+1
    float* __restrict__ out)            // N x C x 16 fp32
{
  const int n = blockIdx.x;
  const int c0 = blockIdx.y * 128;
  const int t = threadIdx.x;
  const int q = t & 1;
  const int cl = t >> 1;
  const int ca = c0 + cl;
  const int ioff = ca * HWSZ + q * 8;   // element offset into image/out row

  const int beg = offsets[n], end = offsets[n + 1];
  f32x4 aA0{0.f,0.f,0.f,0.f}, aA1{0.f,0.f,0.f,0.f};
  f32x4 aB0{0.f,0.f,0.f,0.f}, aB1{0.f,0.f,0.f,0.f};

  int2 p0{0,0}, p1{0,0};
  if (beg < end) p0 = pairs[beg];
  if (beg + 1 < end) p1 = pairs[beg + 1];

  auto edge = [&](int2 cp, f32x4& x0, f32x4& x1) {
    const u16x8 iv = *(const u16x8*)(imgb16 + (size_t)cp.y * CHW + ioff);
    const uint u = *(const uint*)(Eo + (size_t)cp.x * N_DIM + 2 * ca);
    const float g  = __uint_as_float(u << 16);
    const float be = __uint_as_float(u & 0xffff0000u);
    f32x4 i0, i1;
    i0[0] = __uint_as_float((uint)iv[0] << 16);
    i0[1] = __uint_as_float((uint)iv[1] << 16);
    i0[2] = __uint_as_float((uint)iv[2] << 16);
    i0[3] = __uint_as_float((uint)iv[3] << 16);
    i1[0] = __uint_as_float((uint)iv[4] << 16);
    i1[1] = __uint_as_float((uint)iv[5] << 16);
    i1[2] = __uint_as_float((uint)iv[6] << 16);
    i1[3] = __uint_as_float((uint)iv[7] << 16);
    x0 += g * i0 + be;
    x1 += g * i1 + be;
  };

  int ei = beg;
  for (; ei + 1 < end; ei += 2) {
    const int2 c0p = p0, c1p = p1;
    if (ei + 2 < end) p0 = pairs[ei + 2];
    if (ei + 3 < end) p1 = pairs[ei + 3];
    edge(c0p, aA0, aA1);
    edge(c1p, aB0, aB1);
  }
  if (ei < end) edge(p0, aA0, aA1);

  const int cnt = end - beg;
  const float inv = cnt > 0 ? 1.f / (float)cnt : 0.f;
  const f32x4 r0 = (aA0 + aB0) * inv;
  const f32x4 r1 = (aA1 + aB1) * inv;
  float* ob = out + (size_t)n * CHW + ioff;
  __builtin_nontemporal_store(r0, (f32x4*)ob);
  __builtin_nontemporal_store(r1, (f32x4*)(ob + 4));
}

// ---------------- launch ----------------
extern "C" void kernel_launch(void* const* d_in, const int* in_sizes, int n_in,
                              void* d_out, int out_size, void* d_ws, size_t ws_size,
                              hipStream_t stream) {
  const float* pose  = (const float*)d_in[0];
  const float* image = (const float*)d_in[1];
  const float* W1    = (const float*)d_in[2];
  const float* b1    = (const float*)d_in[3];
  const float* W2    = (const float*)d_in[4];
  const float* b2    = (const float*)d_in[5];
  const int*   src   = (const int*)d_in[6];
  const int*   dst   = (const int*)d_in[7];
  const int E = in_sizes[6];                     // 8192
  const int N = in_sizes[1] / CHW;               // 1024
  float* out = (float*)d_out;

  char* ws = (char*)d_ws;
  size_t off = 0;
  auto alloc = [&](size_t bytes) {
    void* p = ws + off;
    off = (off + bytes + 255) & ~(size_t)255;
    return p;
  };
  bf16* h     = (bf16*)alloc((size_t)E * C_DIM * sizeof(bf16));
  bf16* W2t   = (bf16*)alloc((size_t)N_DIM * K_DIM * sizeof(bf16));
  bf16* Eout  = (bf16*)alloc((size_t)E * N_DIM * sizeof(bf16));
  bf16* imgb  = (bf16*)alloc((size_t)N * CHW * sizeof(bf16));
  int* offs   = (int*)alloc((size_t)(N + 1) * sizeof(int));
  int2* pairs = (int2*)alloc((size_t)E * sizeof(int2));

  // prep: CSR + batched pose MLP1 + W2 transpose + image convert, one launch
  const int nb_prep = 1 + (E / EPB) * 5 + (N_DIM / 32) * (K_DIM / 32) + (N * CHW) / 2048;
  prep<<<nb_prep, 256, 0, stream>>>(pose, W1, b1, h, W2, W2t, image, imgb,
                                    dst, src, offs, pairs, E, N);

  // GEMM standalone (m97 128x128 structure, 5 blocks/CU)
  gemm_sigmoid<<<(E / BM) * (N_DIM / BN), 256, 0, stream>>>(h, W2t, b2, Eout);

  // FiLM + segment mean (bf16 image)
  scatter_mean<<<dim3(N, 10), 256, 0, stream>>>(
      (const ushort*)Eout, (const ushort*)imgb, pairs, offs, out);
}